// Round 17
// baseline (61.824 us; speedup 1.0000x reference)
//
#include <hip/hip_runtime.h>
#include <math.h>

typedef unsigned short u16;
typedef unsigned int u32;
typedef __bf16 bf16x8 __attribute__((ext_vector_type(8)));
typedef float f32x4 __attribute__((ext_vector_type(4)));

// Problem constants
#define BB   4      // B
#define DD   256    // d
#define NN   256    // n
#define CH   128    // CHUNK
#define NCH  16     // T/CHUNK
#define EPSF 1e-8f

// Workspace byte offsets
#define WS_QB  0u           // qb   bf16 [T][B][N]          4 MB
#define WS_VT  (4u<<20)     // vT   bf16 [CB][D][S=128]     4 MB
#define WS_WT  (8u<<20)     // wT   bf16 [CB][N][S=128]     4 MB
#define WS_WN  (12u<<20)    // w_n  bf16 [CB][S][N]         4 MB
#define WS_AST (16u<<20)    // AsT  bf16 [CB][T=128][S=128] 2 MB
#define WS_PF  (26u<<20)    // pf   f32  [CB][N]            64 KB
#define WS_UT  (28u<<20)    // utT  bf16 [CB][D][N]         8 MB

__device__ __forceinline__ u16 f2bf(float x) {
  u32 u = __float_as_uint(x);
  u32 r = (u + 0x7fffu + ((u >> 16) & 1u)) >> 16;
  return (u16)r;
}
__device__ __forceinline__ float bf2f(u32 lo16) {
  return __uint_as_float(lo16 << 16);
}

// Bijective XCD swizzle (grid % 8 == 0): contiguous logical ids per XCD.
__device__ __forceinline__ int xcd_swz(int bid, int nwg) {
  return (bid & 7) * (nwg >> 3) + (bid >> 3);
}

__device__ __forceinline__ void gload16(void* lds, const void* g) {
  __builtin_amdgcn_global_load_lds((const __attribute__((address_space(1))) void*)g,
                                   (__attribute__((address_space(3))) void*)lds, 16, 0, 0);
}

// 256-thread stage of a 64x64 bf16 tile (slot-XOR swizzle on GLOBAL src).
__device__ __forceinline__ void stage_tile(u16* lds, const u16* g, int rowstride) {
  int tid = threadIdx.x;
#pragma unroll
  for (int h = 0; h < 2; h++) {
    int ci = tid + h * 256;
    int r = ci >> 3, sl = ci & 7;
    const u16* src = g + (size_t)r * rowstride + ((sl ^ (r & 7)) << 3);
    gload16(lds + (size_t)ci * 8, src);
  }
}

// 512-thread stage of a 128x64 tile (2 chunks/thread).
__device__ __forceinline__ void stageA512(u16* lds, const u16* g, int rowstride) {
  int tid = threadIdx.x;
#pragma unroll
  for (int h = 0; h < 2; h++) {
    int ci = tid + h * 512;
    int r = ci >> 3, sl = ci & 7;
    const u16* src = g + (size_t)r * rowstride + ((sl ^ (r & 7)) << 3);
    gload16(lds + (size_t)ci * 8, src);
  }
}

// 512-thread stage of a 64x64 tile (1 chunk/thread).
__device__ __forceinline__ void stageB512(u16* lds, const u16* g, int rowstride) {
  int ci = threadIdx.x;
  int r = ci >> 3, sl = ci & 7;
  const u16* src = g + (size_t)r * rowstride + ((sl ^ (r & 7)) << 3);
  gload16(lds + (size_t)ci * 8, src);
}

// Read 2x2 fragments with matching swizzle. Chunk index ks*4+(lane>>4) (R7 fix).
__device__ __forceinline__ void read_frags(const u16* buf, int rbase, int lane,
                                           bf16x8 (&f)[2][2]) {
#pragma unroll
  for (int i = 0; i < 2; i++)
#pragma unroll
    for (int ks = 0; ks < 2; ks++) {
      int r = rbase + i * 16 + (lane & 15);
      int slot = ((ks << 2) + (lane >> 4)) ^ (r & 7);
      f[i][ks] = *reinterpret_cast<const bf16x8*>(buf + r * 64 + slot * 8);
    }
}

__device__ __forceinline__ void mma_step(const u16* Ab, const u16* Bb, int rm, int cn,
                                         int lane, f32x4 (&acc)[2][2]) {
  bf16x8 a[2][2], b[2][2];
  read_frags(Ab, rm, lane, a);
  read_frags(Bb, cn, lane, b);
#pragma unroll
  for (int mf = 0; mf < 2; mf++)
#pragma unroll
    for (int nf = 0; nf < 2; nf++)
#pragma unroll
      for (int ks = 0; ks < 2; ks++)
        acc[mf][nf] = __builtin_amdgcn_mfma_f32_16x16x32_bf16(a[mf][ks], b[nf][ks],
                                                              acc[mf][nf], 0, 0, 0);
}

// ---------------------------------------------------------------------------
// k_prep: wpf (bid<256, float4) | trv (bid<512) | convq (bid<1536).  (R14)
__global__ __launch_bounds__(256) void k_prep(const float* __restrict__ q,
                                              const float* __restrict__ v,
                                              const float* __restrict__ kin,
                                              const float* __restrict__ alpha,
                                              u16* __restrict__ qb,
                                              u16* __restrict__ vT,
                                              u16* __restrict__ wT,
                                              u16* __restrict__ wn,
                                              float* __restrict__ pf) {
  __shared__ __align__(16) char smem[64 * 136 * 2];
  int bid = blockIdx.x;
  int tid = threadIdx.x;
  if (bid < 256) {
    int ng = bid & 3, b = (bid >> 2) & 3, c = bid >> 4;
    int lane16 = tid & 15, seg = tid >> 4;
    int n0 = ng * 64 + lane16 * 4;
    int cb = c * BB + b;
    size_t gbase = ((size_t)(c * CH + seg * 8) * 1024) + b * NN + n0;

    float4 lg[8], kv[8];
    float4 a0 = {0.f, 0.f, 0.f, 0.f};
    float4 run = {0.f, 0.f, 0.f, 0.f};
#pragma unroll
    for (int i = 0; i < 8; i++) {
      float4 av = *(const float4*)&alpha[gbase + (size_t)i * 1024];
      av.x = fmaxf(av.x, EPSF); av.y = fmaxf(av.y, EPSF);
      av.z = fmaxf(av.z, EPSF); av.w = fmaxf(av.w, EPSF);
      kv[i] = *(const float4*)&kin[gbase + (size_t)i * 1024];
      if (i == 0) a0 = av;
      run.x += __logf(av.x); run.y += __logf(av.y);
      run.z += __logf(av.z); run.w += __logf(av.w);
      lg[i] = run;
    }

    float4 (*tot)[16] = (float4(*)[16])smem;
    tot[seg][lane16] = run;
    __syncthreads();
    float4 prefix = {0.f, 0.f, 0.f, 0.f}, total = {0.f, 0.f, 0.f, 0.f};
#pragma unroll
    for (int j = 0; j < 16; j++) {
      float4 tv = tot[j][lane16];
      if (j < seg) { prefix.x += tv.x; prefix.y += tv.y; prefix.z += tv.z; prefix.w += tv.w; }
      total.x += tv.x; total.y += tv.y; total.z += tv.z; total.w += tv.w;
    }
    float4 rden;
    rden.x = 1.f / (__expf(total.x) + EPSF);
    rden.y = 1.f / (__expf(total.y) + EPSF);
    rden.z = 1.f / (__expf(total.z) + EPSF);
    rden.w = 1.f / (__expf(total.w) + EPSF);

    union { u16 u[8]; uint4 v4; } pkn[4];
    u16* wncb = wn + (size_t)cb * (CH * NN);
#pragma unroll
    for (int i = 0; i < 8; i++) {
      union { u16 u[4]; uint2 v2; } row;
      row.u[0] = f2bf(kv[i].x * (__expf(prefix.x + lg[i].x) * rden.x));
      row.u[1] = f2bf(kv[i].y * (__expf(prefix.y + lg[i].y) * rden.y));
      row.u[2] = f2bf(kv[i].z * (__expf(prefix.z + lg[i].z) * rden.z));
      row.u[3] = f2bf(kv[i].w * (__expf(prefix.w + lg[i].w) * rden.w));
      pkn[0].u[i] = row.u[0]; pkn[1].u[i] = row.u[1];
      pkn[2].u[i] = row.u[2]; pkn[3].u[i] = row.u[3];
      *(uint2*)(wncb + (size_t)(seg * 8 + i) * NN + n0) = row.v2;
    }
    u16* wtcb = wT + (size_t)cb * (NN * CH);
#pragma unroll
    for (int j = 0; j < 4; j++)
      *(uint4*)(wtcb + (size_t)(n0 + j) * CH + seg * 8) = pkn[j].v4;
    if (seg == 0) *(float4*)&pf[cb * NN + n0] = a0;
  } else if (bid < 512) {
    int b2 = bid - 256;
    int dt = b2 & 3, cb = b2 >> 2;
    int c = cb >> 2, b = cb & 3;
    int d0 = dt * 64;
    u16* vt = (u16*)smem;  // [64][136]
    int sr = tid >> 4, chd = tid & 15;
#pragma unroll
    for (int p = 0; p < 8; p++) {
      int s = p * 16 + sr;
      float4 x = *(const float4*)&v[((size_t)(c * CH + s) * BB + b) * DD + d0 + chd * 4];
      int dbase = chd * 4;
      vt[(dbase + 0) * 136 + s] = f2bf(x.x);
      vt[(dbase + 1) * 136 + s] = f2bf(x.y);
      vt[(dbase + 2) * 136 + s] = f2bf(x.z);
      vt[(dbase + 3) * 136 + s] = f2bf(x.w);
    }
    __syncthreads();
    int dr = tid >> 2, ch = tid & 3;
    const uint4* srcl = (const uint4*)&vt[dr * 136 + ch * 32];
    uint4 a0 = srcl[0], a1 = srcl[1], a2 = srcl[2], a3 = srcl[3];
    uint4* dst = (uint4*)&vT[((size_t)cb * DD + d0 + dr) * CH + ch * 32];
    dst[0] = a0; dst[1] = a1; dst[2] = a2; dst[3] = a3;
  } else {
    size_t gid = (size_t)(bid - 512) * 256 + tid;
    const float4* src = (const float4*)q + gid * 2;
    float4 x = src[0], z = src[1];
    union { u16 u[8]; uint4 v4; } pk;
    pk.u[0] = f2bf(x.x); pk.u[1] = f2bf(x.y); pk.u[2] = f2bf(x.z); pk.u[3] = f2bf(x.w);
    pk.u[4] = f2bf(z.x); pk.u[5] = f2bf(z.y); pk.u[6] = f2bf(z.z); pk.u[7] = f2bf(z.w);
    ((uint4*)qb)[gid] = pk.v4;
  }
}

// ---------------------------------------------------------------------------
// k_utas: bid<192 -> As GEMM (long blocks FIRST); bid>=192 -> UT GEMM
// (1024 blocks, XCD-swizzled, R14's single-stage K=128). Both depend only
// on prep outputs.
__global__ __launch_bounds__(256) void k_utas(const u16* __restrict__ vT,
                                              const u16* __restrict__ wT,
                                              const u16* __restrict__ qb,
                                              const u16* __restrict__ wn,
                                              u16* __restrict__ utb,
                                              u16* __restrict__ asT) {
  __shared__ u16 Al[2][4096], Bl[2][4096];
  int bid0 = blockIdx.x;
  int tid = threadIdx.x, lane = tid & 63, wv = tid >> 6;
  int rm = (wv >> 1) * 32, cn = (wv & 1) * 32;
  if (bid0 < 192) {
    int tile = bid0 % 3;
    int cb = bid0 / 3;
    int ti = (tile == 0) ? 0 : 1;
    int si = (tile == 2) ? 1 : 0;
    int t0 = ti * 64, s0 = si * 64;
    int c = cb >> 2, b = cb & 3;
    const u16* A = qb + ((size_t)(c * CH + t0) * BB + b) * NN;    // stride 1024
    const u16* B = wn + (size_t)cb * (CH * NN) + (size_t)s0 * NN; // stride 256
    f32x4 acc[2][2] = {};
    stage_tile(Al[0], A, BB * NN); stage_tile(Bl[0], B, NN);
    __syncthreads();
    for (int st = 0; st < 4; st++) {
      int nx = st + 1;
      if (nx < 4) {
        stage_tile(Al[nx & 1], A + nx * 64, BB * NN);
        stage_tile(Bl[nx & 1], B + nx * 64, NN);
      }
      mma_step(Al[st & 1], Bl[st & 1], rm, cn, lane, acc);
      __syncthreads();
    }
    u16* outb = asT + (size_t)cb * (CH * CH);
#pragma unroll
    for (int mf = 0; mf < 2; mf++)
#pragma unroll
      for (int nf = 0; nf < 2; nf++)
#pragma unroll
        for (int r = 0; r < 4; r++) {
          int t = t0 + rm + mf * 16 + (lane >> 4) * 4 + r;
          int s = s0 + cn + nf * 16 + (lane & 15);
          float val = (s <= t) ? acc[mf][nf][r] : 0.f;
          outb[(size_t)t * CH + s] = f2bf(val);
        }
  } else {
    int bid = xcd_swz(bid0 - 192, 1024);
    int nt = bid & 3, dt = (bid >> 2) & 3, cb = bid >> 4;
    const u16* A = vT + ((size_t)cb * DD + dt * 64) * CH;
    const u16* B = wT + ((size_t)cb * NN + nt * 64) * CH;
    f32x4 acc[2][2] = {};
    stage_tile(Al[0], A, CH); stage_tile(Al[1], A + 64, CH);
    stage_tile(Bl[0], B, CH); stage_tile(Bl[1], B + 64, CH);
    __syncthreads();
    mma_step(Al[0], Bl[0], rm, cn, lane, acc);
    mma_step(Al[1], Bl[1], rm, cn, lane, acc);
    u16* out = utb + ((size_t)cb * DD + dt * 64) * NN + nt * 64;
#pragma unroll
    for (int mf = 0; mf < 2; mf++)
#pragma unroll
      for (int nf = 0; nf < 2; nf++)
#pragma unroll
        for (int r = 0; r < 4; r++) {
          int row = rm + mf * 16 + (lane >> 4) * 4 + r;
          int col = cn + nf * 16 + (lane & 15);
          out[(size_t)row * NN + col] = f2bf(acc[mf][nf][r]);
        }
  }
}

// ---------------------------------------------------------------------------
// k_outscan: 256 blocks x 512 thr. Block (cb, dt) recomputes its scan slice
// (32 S f32/thread over prior chunks, utb L2/L3-hot), writes the 64d x 256n
// sptT tile DIRECTLY into LDS pre-swizzled (no B1 staging), then runs
// phase-1 (K=256, n) + phase-2 (K=128, s; causal guard on stage 5).
// A1-stage-0 issued BEFORE the scan so HBM latency hides under scan VALU.
__global__ __launch_bounds__(512) void k_outscan(const u16* __restrict__ qb,
                                                 const u16* __restrict__ asT,
                                                 const u16* __restrict__ vT,
                                                 const u16* __restrict__ utb,
                                                 const float* __restrict__ pf,
                                                 float* __restrict__ y) {
  __shared__ u16 Al[2][8192];    // A dbuf: 128 x 64
  __shared__ u16 Bl2[2][4096];   // phase-2 B dbuf: 64 x 64
  __shared__ u16 bspt[4][4096];  // sptT tile: 4 n-stages of [64 d][64 n]
  int bid = xcd_swz(blockIdx.x, 256);
  int dt = bid & 3, cb = bid >> 2;
  int c = cb >> 2, b = cb & 3;
  int d0 = dt * 64;
  int tid = threadIdx.x, lane = tid & 63, wv = tid >> 6;
  int rm = (wv >> 1) * 32, cn = (wv & 1) * 32;  // 8 waves: rm 0..96, cn 0/32
  const u16* A1 = qb + ((size_t)(c * CH) * BB + b) * NN;   // 128 t rows, stride 1024
  const u16* A2 = asT + (size_t)cb * (CH * CH);            // 128 t rows, stride 128
  const u16* B2 = vT + ((size_t)cb * DD + d0) * CH;        // 64 d rows, stride 128

  stageA512(Al[0], A1, BB * NN);  // issue early; drained by the barrier below

  // ---- in-block scan: thread owns d-row (tid>>3), 32 n at (tid&7)*32 ----
  int row = tid >> 3;
  int dr = d0 + row;
  int n8 = (tid & 7) * 32;
  float S[32];
#pragma unroll
  for (int j = 0; j < 32; j++) S[j] = 0.f;
  for (int cp = 0; cp < c; cp++) {
    int cbp = cp * BB + b;
    const u32* urow = (const u32*)(utb + ((size_t)cbp * DD + dr) * NN + n8);
    u32 ub[16];
#pragma unroll
    for (int j = 0; j < 16; j++) ub[j] = urow[j];
#pragma unroll
    for (int j = 0; j < 16; j++) {
      float2 p = *(const float2*)&pf[cbp * NN + n8 + 2 * j];
      S[2 * j]     = S[2 * j]     * p.x + bf2f(ub[j] & 0xffffu);
      S[2 * j + 1] = S[2 * j + 1] * p.y + bf2f(ub[j] >> 16);
    }
  }
  {
    int cbc = c * BB + b;
    int stg = (tid & 7) >> 1, half = tid & 1;
#pragma unroll
    for (int sl = 0; sl < 4; sl++) {
      int col8 = half * 4 + sl;
      int swsl = col8 ^ (row & 7);
      union { u16 u[8]; uint4 v4; } pk;
#pragma unroll
      for (int e = 0; e < 8; e++) {
        float p = pf[cbc * NN + n8 + sl * 8 + e];
        pk.u[e] = f2bf(S[sl * 8 + e] * p);
      }
      *(uint4*)&bspt[stg][row * 64 + swsl * 8] = pk.v4;
    }
  }
  __syncthreads();  // drains A1-stage-0 gloads AND bspt ds_writes

  f32x4 acc[2][2] = {};
  for (int st = 0; st < 6; st++) {
    int nx = st + 1;
    if (nx < 4) {
      stageA512(Al[nx & 1], A1 + nx * 64, BB * NN);
    } else if (nx < 6) {
      stageA512(Al[nx & 1], A2 + (nx - 4) * 64, CH);
      stageB512(Bl2[nx & 1], B2 + (nx - 4) * 64, CH);
    }
    const u16* Bb = (st < 4) ? &bspt[st][0] : Bl2[st & 1];
    if (st < 5 || rm >= 64)  // stage 5: only t>=64 rows valid (causal zeros)
      mma_step(Al[st & 1], Bb, rm, cn, lane, acc);
    __syncthreads();
  }

  float* out = y + ((size_t)(c * CH) * BB + b) * DD + d0;
#pragma unroll
  for (int mf = 0; mf < 2; mf++)
#pragma unroll
    for (int nf = 0; nf < 2; nf++)
#pragma unroll
      for (int r = 0; r < 4; r++) {
        int orow = rm + mf * 16 + (lane >> 4) * 4 + r;
        int col = cn + nf * 16 + (lane & 15);
        out[(size_t)orow * (BB * DD) + col] = acc[mf][nf][r];
      }
}

// ---------------------------------------------------------------------------
extern "C" void kernel_launch(void* const* d_in, const int* in_sizes, int n_in,
                              void* d_out, int out_size, void* d_ws, size_t ws_size,
                              hipStream_t stream) {
  const float* v = (const float*)d_in[0];
  const float* k = (const float*)d_in[1];
  const float* alpha = (const float*)d_in[2];
  const float* q = (const float*)d_in[3];
  float* y = (float*)d_out;
  char* ws = (char*)d_ws;
  u16* qb = (u16*)(ws + WS_QB);
  u16* vT = (u16*)(ws + WS_VT);
  u16* wT = (u16*)(ws + WS_WT);
  u16* wn = (u16*)(ws + WS_WN);
  u16* asT = (u16*)(ws + WS_AST);
  float* pf = (float*)(ws + WS_PF);
  u16* utb = (u16*)(ws + WS_UT);

  k_prep<<<1536, 256, 0, stream>>>(q, v, k, alpha, qb, vT, wT, wn, pf);
  k_utas<<<1216, 256, 0, stream>>>(vT, wT, qb, wn, utb, asT);
  k_outscan<<<256, 512, 0, stream>>>(qb, asT, vT, utb, pf, y);
}

// Round 18
// 33.413 us; speedup vs baseline: 1.8503x; 1.8503x over previous
//
#include <hip/hip_runtime.h>
#include <math.h>

typedef unsigned short u16;
typedef unsigned int u32;
typedef __bf16 bf16x8 __attribute__((ext_vector_type(8)));
typedef float f32x4 __attribute__((ext_vector_type(4)));

// Problem constants
#define BB   4      // B
#define DD   256    // d
#define NN   256    // n
#define CH   128    // CHUNK
#define NCH  16     // T/CHUNK
#define EPSF 1e-8f

// Workspace byte offsets
#define WS_QB  0u           // qb   bf16 [T][B][N]          4 MB
#define WS_VT  (4u<<20)     // vT   bf16 [CB][D][S=128]     4 MB
#define WS_WT  (8u<<20)     // wT   bf16 [CB][N][S=128]     4 MB
#define WS_WN  (12u<<20)    // w_n  bf16 [CB][S][N]         4 MB
#define WS_AST (16u<<20)    // AsT  bf16 [CB][T=128][S=128] 2 MB
#define WS_SPT (18u<<20)    // sptT bf16 [CB][D][N]         8 MB
#define WS_PF  (26u<<20)    // pf   f32  [CB][N]            64 KB
#define WS_UT  (28u<<20)    // utT  bf16 [CB][D][N]         8 MB

__device__ __forceinline__ u16 f2bf(float x) {
  u32 u = __float_as_uint(x);
  u32 r = (u + 0x7fffu + ((u >> 16) & 1u)) >> 16;
  return (u16)r;
}
__device__ __forceinline__ float bf2f(u32 lo16) {
  return __uint_as_float(lo16 << 16);
}

// Bijective XCD swizzle (grid % 8 == 0): contiguous logical ids per XCD.
__device__ __forceinline__ int xcd_swz(int bid, int nwg) {
  return (bid & 7) * (nwg >> 3) + (bid >> 3);
}

__device__ __forceinline__ void gload16(void* lds, const void* g) {
  __builtin_amdgcn_global_load_lds((const __attribute__((address_space(1))) void*)g,
                                   (__attribute__((address_space(3))) void*)lds, 16, 0, 0);
}

// Stage a 64x64 bf16 tile (row-major, rowstride in elems) into linear LDS.
// Slot-XOR swizzle applied on the GLOBAL source address (m173 pattern).
// 2 gload16 (= 2 vm wave-instructions) per thread per call.
__device__ __forceinline__ void stage_tile(u16* lds, const u16* g, int rowstride) {
  int tid = threadIdx.x;
#pragma unroll
  for (int h = 0; h < 2; h++) {
    int ci = tid + h * 256;
    int r = ci >> 3, sl = ci & 7;
    const u16* src = g + (size_t)r * rowstride + ((sl ^ (r & 7)) << 3);
    gload16(lds + (size_t)ci * 8, src);
  }
}

// Read 2x2 fragments with matching swizzle. Chunk index ks*4+(lane>>4) (R7 fix).
__device__ __forceinline__ void read_frags(const u16* buf, int rbase, int lane,
                                           bf16x8 (&f)[2][2]) {
#pragma unroll
  for (int i = 0; i < 2; i++)
#pragma unroll
    for (int ks = 0; ks < 2; ks++) {
      int r = rbase + i * 16 + (lane & 15);
      int slot = ((ks << 2) + (lane >> 4)) ^ (r & 7);
      f[i][ks] = *reinterpret_cast<const bf16x8*>(buf + r * 64 + slot * 8);
    }
}

__device__ __forceinline__ void mma_step(const u16* Ab, const u16* Bb, int rm, int cn,
                                         int lane, f32x4 (&acc)[2][2]) {
  bf16x8 a[2][2], b[2][2];
  read_frags(Ab, rm, lane, a);
  read_frags(Bb, cn, lane, b);
#pragma unroll
  for (int mf = 0; mf < 2; mf++)
#pragma unroll
    for (int nf = 0; nf < 2; nf++)
#pragma unroll
      for (int ks = 0; ks < 2; ks++)
        acc[mf][nf] = __builtin_amdgcn_mfma_f32_16x16x32_bf16(a[mf][ks], b[nf][ks],
                                                              acc[mf][nf], 0, 0, 0);
}

// ---------------------------------------------------------------------------
// k_prep: wpf (bid<256, float4-coalesced) | trv (bid<512) | convq (bid<1536).
__global__ __launch_bounds__(256) void k_prep(const float* __restrict__ q,
                                              const float* __restrict__ v,
                                              const float* __restrict__ kin,
                                              const float* __restrict__ alpha,
                                              u16* __restrict__ qb,
                                              u16* __restrict__ vT,
                                              u16* __restrict__ wT,
                                              u16* __restrict__ wn,
                                              float* __restrict__ pf) {
  __shared__ __align__(16) char smem[64 * 136 * 2];
  int bid = blockIdx.x;
  int tid = threadIdx.x;
  if (bid < 256) {
    // ---- wpf v3: segmented scan, 4 n per thread (float4 loads, 1KB/wave) ----
    int ng = bid & 3, b = (bid >> 2) & 3, c = bid >> 4;
    int lane16 = tid & 15, seg = tid >> 4;   // 16 segs x 8 s
    int n0 = ng * 64 + lane16 * 4;
    int cb = c * BB + b;
    size_t gbase = ((size_t)(c * CH + seg * 8) * 1024) + b * NN + n0;

    float4 lg[8], kv[8];
    float4 a0 = {0.f, 0.f, 0.f, 0.f};
    float4 run = {0.f, 0.f, 0.f, 0.f};
#pragma unroll
    for (int i = 0; i < 8; i++) {
      float4 av = *(const float4*)&alpha[gbase + (size_t)i * 1024];
      av.x = fmaxf(av.x, EPSF); av.y = fmaxf(av.y, EPSF);
      av.z = fmaxf(av.z, EPSF); av.w = fmaxf(av.w, EPSF);
      kv[i] = *(const float4*)&kin[gbase + (size_t)i * 1024];
      if (i == 0) a0 = av;
      run.x += __logf(av.x); run.y += __logf(av.y);
      run.z += __logf(av.z); run.w += __logf(av.w);
      lg[i] = run;
    }

    float4 (*tot)[16] = (float4(*)[16])smem;   // [16 seg][16 lane] f32x4 = 4KB
    tot[seg][lane16] = run;
    __syncthreads();
    float4 prefix = {0.f, 0.f, 0.f, 0.f}, total = {0.f, 0.f, 0.f, 0.f};
#pragma unroll
    for (int j = 0; j < 16; j++) {
      float4 tv = tot[j][lane16];
      if (j < seg) { prefix.x += tv.x; prefix.y += tv.y; prefix.z += tv.z; prefix.w += tv.w; }
      total.x += tv.x; total.y += tv.y; total.z += tv.z; total.w += tv.w;
    }
    float4 rden;
    rden.x = 1.f / (__expf(total.x) + EPSF);
    rden.y = 1.f / (__expf(total.y) + EPSF);
    rden.z = 1.f / (__expf(total.z) + EPSF);
    rden.w = 1.f / (__expf(total.w) + EPSF);

    union { u16 u[8]; uint4 v4; } pkn[4];
    u16* wncb = wn + (size_t)cb * (CH * NN);
#pragma unroll
    for (int i = 0; i < 8; i++) {
      union { u16 u[4]; uint2 v2; } row;
      row.u[0] = f2bf(kv[i].x * (__expf(prefix.x + lg[i].x) * rden.x));
      row.u[1] = f2bf(kv[i].y * (__expf(prefix.y + lg[i].y) * rden.y));
      row.u[2] = f2bf(kv[i].z * (__expf(prefix.z + lg[i].z) * rden.z));
      row.u[3] = f2bf(kv[i].w * (__expf(prefix.w + lg[i].w) * rden.w));
      pkn[0].u[i] = row.u[0]; pkn[1].u[i] = row.u[1];
      pkn[2].u[i] = row.u[2]; pkn[3].u[i] = row.u[3];
      *(uint2*)(wncb + (size_t)(seg * 8 + i) * NN + n0) = row.v2;
    }
    u16* wtcb = wT + (size_t)cb * (NN * CH);
#pragma unroll
    for (int j = 0; j < 4; j++)
      *(uint4*)(wtcb + (size_t)(n0 + j) * CH + seg * 8) = pkn[j].v4;
    if (seg == 0) *(float4*)&pf[cb * NN + n0] = a0;
  } else if (bid < 512) {
    // ---- trv: v -> vT transpose ----
    int b2 = bid - 256;
    int dt = b2 & 3, cb = b2 >> 2;
    int c = cb >> 2, b = cb & 3;
    int d0 = dt * 64;
    u16* vt = (u16*)smem;  // [64][136]
    int sr = tid >> 4, chd = tid & 15;
#pragma unroll
    for (int p = 0; p < 8; p++) {
      int s = p * 16 + sr;
      float4 x = *(const float4*)&v[((size_t)(c * CH + s) * BB + b) * DD + d0 + chd * 4];
      int dbase = chd * 4;
      vt[(dbase + 0) * 136 + s] = f2bf(x.x);
      vt[(dbase + 1) * 136 + s] = f2bf(x.y);
      vt[(dbase + 2) * 136 + s] = f2bf(x.z);
      vt[(dbase + 3) * 136 + s] = f2bf(x.w);
    }
    __syncthreads();
    int dr = tid >> 2, ch = tid & 3;
    const uint4* srcl = (const uint4*)&vt[dr * 136 + ch * 32];
    uint4 a0 = srcl[0], a1 = srcl[1], a2 = srcl[2], a3 = srcl[3];
    uint4* dst = (uint4*)&vT[((size_t)cb * DD + d0 + dr) * CH + ch * 32];
    dst[0] = a0; dst[1] = a1; dst[2] = a2; dst[3] = a3;
  } else {
    // ---- convq: q fp32 -> qb bf16 ----
    size_t gid = (size_t)(bid - 512) * 256 + tid;
    const float4* src = (const float4*)q + gid * 2;
    float4 x = src[0], z = src[1];
    union { u16 u[8]; uint4 v4; } pk;
    pk.u[0] = f2bf(x.x); pk.u[1] = f2bf(x.y); pk.u[2] = f2bf(x.z); pk.u[3] = f2bf(x.w);
    pk.u[4] = f2bf(z.x); pk.u[5] = f2bf(z.y); pk.u[6] = f2bf(z.z); pk.u[7] = f2bf(z.w);
    ((uint4*)qb)[gid] = pk.v4;
  }
}

// ---------------------------------------------------------------------------
// k_ut: UT GEMM only (uniform, 1024 blocks, XCD-swizzled; single-stage K=128).
__global__ __launch_bounds__(256) void k_ut(const u16* __restrict__ vT,
                                            const u16* __restrict__ wT,
                                            u16* __restrict__ utb) {
  __shared__ u16 Al[2][4096], Bl[2][4096];
  int bid = xcd_swz(blockIdx.x, 1024);
  int tid = threadIdx.x, lane = tid & 63, wv = tid >> 6;
  int rm = (wv >> 1) * 32, cn = (wv & 1) * 32;
  int nt = bid & 3, dt = (bid >> 2) & 3, cb = bid >> 4;
  const u16* A = vT + ((size_t)cb * DD + dt * 64) * CH;
  const u16* B = wT + ((size_t)cb * NN + nt * 64) * CH;
  f32x4 acc[2][2] = {};
  stage_tile(Al[0], A, CH); stage_tile(Al[1], A + 64, CH);
  stage_tile(Bl[0], B, CH); stage_tile(Bl[1], B + 64, CH);
  __syncthreads();
  mma_step(Al[0], Bl[0], rm, cn, lane, acc);
  mma_step(Al[1], Bl[1], rm, cn, lane, acc);
  u16* out = utb + ((size_t)cb * DD + dt * 64) * NN + nt * 64;
#pragma unroll
  for (int mf = 0; mf < 2; mf++)
#pragma unroll
    for (int nf = 0; nf < 2; nf++)
#pragma unroll
      for (int r = 0; r < 4; r++) {
        int row = rm + mf * 16 + (lane >> 4) * 4 + r;
        int col = cn + nf * 16 + (lane & 15);
        out[(size_t)row * NN + col] = f2bf(acc[mf][nf][r]);
      }
}

// ---------------------------------------------------------------------------
// k_scanas: bid<192 -> As GEMM (2-buffer, 32KB LDS -> all 704 co-resident);
//           bid in [192,704) -> scan.
__global__ __launch_bounds__(256) void k_scanas(const u16* __restrict__ qb,
                                                const u16* __restrict__ wn,
                                                const u32* __restrict__ utT2,
                                                const float* __restrict__ pf,
                                                u16* __restrict__ asT,
                                                u32* __restrict__ sptT2) {
  __shared__ u16 Al[2][4096], Bl[2][4096];  // 32 KB
  int bid = blockIdx.x;
  int tid = threadIdx.x;
  if (bid < 192) {
    int lane = tid & 63, wv = tid >> 6;
    int rm = (wv >> 1) * 32, cn = (wv & 1) * 32;
    int tile = bid % 3;
    int cb = bid / 3;
    int ti = (tile == 0) ? 0 : 1;
    int si = (tile == 2) ? 1 : 0;
    int t0 = ti * 64, s0 = si * 64;
    int c = cb >> 2, b = cb & 3;
    const u16* A = qb + ((size_t)(c * CH + t0) * BB + b) * NN;    // stride 1024
    const u16* B = wn + (size_t)cb * (CH * NN) + (size_t)s0 * NN; // stride 256
    f32x4 acc[2][2] = {};
    stage_tile(Al[0], A, BB * NN); stage_tile(Bl[0], B, NN);
    __syncthreads();
    for (int st = 0; st < 4; st++) {
      int nx = st + 1;
      if (nx < 4) {
        stage_tile(Al[nx & 1], A + nx * 64, BB * NN);
        stage_tile(Bl[nx & 1], B + nx * 64, NN);
      }
      mma_step(Al[st & 1], Bl[st & 1], rm, cn, lane, acc);
      __syncthreads();
    }
    u16* outb = asT + (size_t)cb * (CH * CH);
#pragma unroll
    for (int mf = 0; mf < 2; mf++)
#pragma unroll
      for (int nf = 0; nf < 2; nf++)
#pragma unroll
        for (int r = 0; r < 4; r++) {
          int t = t0 + rm + mf * 16 + (lane >> 4) * 4 + r;
          int s = s0 + cn + nf * 16 + (lane & 15);
          float val = (s <= t) ? acc[mf][nf][r] : 0.f;
          outb[(size_t)t * CH + s] = f2bf(val);
        }
  } else {
    // ---- scan: batched loads, serial S-update. 512 works, 1 u32/thread.
    int id = (bid - 192) * 256 + tid;
    int nh = id & 127, dd = (id >> 7) & 255, b = id >> 15;
    u32 u[NCH];
    float2 pp[NCH];
#pragma unroll
    for (int ch = 0; ch < NCH; ch++) {
      int cb = ch * BB + b;
      u[ch] = utT2[((size_t)cb * DD + dd) * 128 + nh];
      pp[ch] = *(const float2*)&pf[cb * NN + nh * 2];
    }
    float S0 = 0.f, S1 = 0.f;
#pragma unroll
    for (int ch = 0; ch < NCH; ch++) {
      int cb = ch * BB + b;
      float Sp0 = S0 * pp[ch].x, Sp1 = S1 * pp[ch].y;
      sptT2[((size_t)cb * DD + dd) * 128 + nh] = (u32)f2bf(Sp0) | ((u32)f2bf(Sp1) << 16);
      S0 = Sp0 + bf2f(u[ch] & 0xffffu);
      S1 = Sp1 + bf2f(u[ch] >> 16);
    }
  }
}

// ---------------------------------------------------------------------------
// k_out (MFMA): y[t,d] = sum_n qb[t,n]*sptT[d,n] + sum_s AsT[t,s]*vT[d,s].
// 3-buffer counted-vmcnt pipeline (R13, measured neutral/safe).
__global__ __launch_bounds__(256) void k_out(const u16* __restrict__ qb,
                                             const u16* __restrict__ sptT,
                                             const u16* __restrict__ asT,
                                             const u16* __restrict__ vT,
                                             float* __restrict__ y) {
  int bid = xcd_swz(blockIdx.x, 512);
  int dt = bid & 3, tt = (bid >> 2) & 1, cb = bid >> 3;
  int c = cb >> 2, b = cb & 3;
  int t0 = tt * 64, d0 = dt * 64;
  int tid = threadIdx.x, lane = tid & 63, wv = tid >> 6;
  int rm = (wv >> 1) * 32, cn = (wv & 1) * 32;
  const u16* A1 = qb + ((size_t)(c * CH + t0) * BB + b) * NN;      // stride 1024
  const u16* B1 = sptT + ((size_t)cb * DD + d0) * NN;              // stride 256
  const u16* A2 = asT + (size_t)cb * (CH * CH) + (size_t)t0 * CH;  // stride 128
  const u16* B2 = vT + ((size_t)cb * DD + d0) * CH;                // stride 128
  __shared__ u16 Al[3][4096], Bl[3][4096];  // 48 KB -> 3 blocks/CU
  f32x4 acc[2][2] = {};
  int nst = 5 + tt;  // tt=0: s in [0,64) only (rest masked zero, never read)

#define STG_OUT(s)                                                   \
  do {                                                               \
    if ((s) < 4) {                                                   \
      stage_tile(Al[(s) % 3], A1 + (s) * 64, BB * NN);               \
      stage_tile(Bl[(s) % 3], B1 + (s) * 64, NN);                    \
    } else {                                                         \
      stage_tile(Al[(s) % 3], A2 + ((s) - 4) * 64, CH);              \
      stage_tile(Bl[(s) % 3], B2 + ((s) - 4) * 64, CH);              \
    }                                                                \
  } while (0)

  STG_OUT(0);
  STG_OUT(1);
  asm volatile("s_waitcnt vmcnt(4)" ::: "memory");
  __builtin_amdgcn_sched_barrier(0);
  __builtin_amdgcn_s_barrier();

  for (int st = 0; st < nst; st++) {
    bool more = (st + 2 < nst);
    if (more) STG_OUT(st + 2);
    mma_step(Al[st % 3], Bl[st % 3], rm, cn, lane, acc);
    if (st + 1 < nst) {
      if (more) asm volatile("s_waitcnt vmcnt(4)" ::: "memory");
      else      asm volatile("s_waitcnt vmcnt(0)" ::: "memory");
      __builtin_amdgcn_sched_barrier(0);
      __builtin_amdgcn_s_barrier();
    }
  }
#undef STG_OUT

  float* out = y + ((size_t)(c * CH + t0) * BB + b) * DD + d0;
#pragma unroll
  for (int mf = 0; mf < 2; mf++)
#pragma unroll
    for (int nf = 0; nf < 2; nf++)
#pragma unroll
      for (int r = 0; r < 4; r++) {
        int row = rm + mf * 16 + (lane >> 4) * 4 + r;
        int col = cn + nf * 16 + (lane & 15);
        out[(size_t)row * (BB * DD) + col] = acc[mf][nf][r];
      }
}

// ---------------------------------------------------------------------------
extern "C" void kernel_launch(void* const* d_in, const int* in_sizes, int n_in,
                              void* d_out, int out_size, void* d_ws, size_t ws_size,
                              hipStream_t stream) {
  const float* v = (const float*)d_in[0];
  const float* k = (const float*)d_in[1];
  const float* alpha = (const float*)d_in[2];
  const float* q = (const float*)d_in[3];
  float* y = (float*)d_out;
  char* ws = (char*)d_ws;
  u16* qb = (u16*)(ws + WS_QB);
  u16* vT = (u16*)(ws + WS_VT);
  u16* wT = (u16*)(ws + WS_WT);
  u16* wn = (u16*)(ws + WS_WN);
  u16* asT = (u16*)(ws + WS_AST);
  u16* sptT = (u16*)(ws + WS_SPT);
  float* pf = (float*)(ws + WS_PF);
  u16* utb = (u16*)(ws + WS_UT);

  k_prep<<<1536, 256, 0, stream>>>(q, v, k, alpha, qb, vT, wT, wn, pf);
  k_ut<<<1024, 256, 0, stream>>>(vT, wT, utb);
  k_scanas<<<704, 256, 0, stream>>>(qb, wn, (const u32*)utb, pf, asT, (u32*)sptT);
  k_out<<<512, 256, 0, stream>>>(qb, sptT, asT, vT, y);
}